// Round 13
// baseline (98.967 us; speedup 1.0000x reference)
//
#include <hip/hip_runtime.h>

// SSD MultiBoxLoss: B=64, P=29126, G=24, 2 classes, scalar fp32 output.
// Sparse matching -> byte flags; chunked loss with wave-aggregated histogram
// (kills LDS same-bin atomic serialization) + LDS override table.
static constexpr int B_ = 64;
static constexpr int P_ = 29126;
static constexpr int G_ = 24;
static constexpr float THRESH_ = 0.35f;
static constexpr int NEGPOS_ = 7;
static constexpr int PBC_ = (P_ + 2047) / 2048;  // 15 chunked p-blocks
static constexpr int NBLK_ = PBC_ * B_;          // 960 partial slots
static constexpr int CCSTRIDE_ = 32;             // candCount stride = 128 B

// zeroed region: match (B*P bytes) + hist1 (B*4096 u32) + candCount
static constexpr size_t ZBYTES_ =
    (size_t)B_*P_ + (size_t)B_*4096*4 + (size_t)B_*CCSTRIDE_*4;
static constexpr int ZVEC_ = (int)((ZBYTES_ + 15) / 16);   // ulonglong2 units

// ---------------------------------------------------------------- kernel 0
__global__ __launch_bounds__(256) void k_zero(ulonglong2* __restrict__ dst)
{
    const int i = blockIdx.x*256 + threadIdx.x;
    if (i < ZVEC_) dst[i] = make_ulonglong2(0ull, 0ull);
}

// ---------------------------------------------------------------- kernel 1
// One block per (b,g). Enumerate intersecting priors.
//   match[b,p] = 1 (plain byte store) when iou >= THRESH  -- no atomics.
//   bp_pack[b,g] = (iou_bits<<32)|~p  (tie => min p), plain store.
__global__ __launch_bounds__(256) void k_sparse(
    const float4* __restrict__ gt4,      // [B*G] point-form
    const float4* __restrict__ priors4,  // [P]  (cx,cy,w,h)
    unsigned char* __restrict__ match,   // [B*P], zeroed
    unsigned long long* __restrict__ bp_pack)   // [B*G]
{
    const int g = blockIdx.x;            // G_
    const int b = blockIdx.y;            // B_
    const int bg = b*G_ + g;
    const int tid = threadIdx.x;

    const float4 t = gt4[bg];
    const float area_t = (t.z - t.x) * (t.w - t.y);

    float bv = -1.0f; int bq = 0;

#pragma unroll
    for (int r = 0; r < 6; ++r) {
        const int   f    = (r < 2) ? 105 : (r < 4) ? 53 : 27;
        const float sc   = (r < 2) ? 105.0f : (r < 4) ? 52.5f : 26.25f; // 840/step
        const int   base = (r == 0) ? 0 : (r == 1) ? 11025 : (r == 2) ? 22050
                         : (r == 3) ? 24859 : (r == 4) ? 27668 : 28397;
        const float hw   = ((r == 0) ? 16.0f : (r == 1) ? 32.0f : (r == 2) ? 64.0f
                         : (r == 3) ? 128.0f : (r == 4) ? 256.0f : 512.0f)
                           * (0.5f / 840.0f);

        const int j0 = max(0,     (int)floorf((t.x - hw)*sc - 0.5f) - 1);
        const int j1 = min(f - 1, (int)ceilf ((t.z + hw)*sc - 0.5f) + 1);
        const int i0 = max(0,     (int)floorf((t.y - hw)*sc - 0.5f) - 1);
        const int i1 = min(f - 1, (int)ceilf ((t.w + hw)*sc - 0.5f) + 1);
        const int W = j1 - j0 + 1;
        const int n = W * (i1 - i0 + 1);

        for (int c = tid; c < n; c += 256) {
            const int ii = c / W;
            const int jj = c - ii*W;
            const int p = base + (i0 + ii)*f + (j0 + jj);
            const float4 pr = priors4[p];
            const float hx = pr.z * 0.5f, hy = pr.w * 0.5f;
            const float px0 = pr.x - hx, py0 = pr.y - hy;
            const float px1 = pr.x + hx, py1 = pr.y + hy;
            const float area_p = (px1 - px0) * (py1 - py0);
            const float lx = fmaxf(t.x, px0), ly = fmaxf(t.y, py0);
            const float rx = fminf(t.z, px1), ry = fminf(t.w, py1);
            const float iw = fmaxf(rx - lx, 0.0f), ih = fmaxf(ry - ly, 0.0f);
            const float inter = iw * ih;
            const float iou = __fdividef(inter, (area_t + area_p) - inter);

            if (iou >= THRESH_) match[(size_t)b*P_ + p] = 1;
            if (iou > bv) { bv = iou; bq = p; }   // increasing p => min-p tie
        }
    }

    // block argmax (max iou, tie => min p)
    const int lane = tid & 63, wave = tid >> 6;
    for (int m = 32; m; m >>= 1) {
        const float ov = __shfl_xor(bv, m, 64);
        const int   oq = __shfl_xor(bq, m, 64);
        if (ov > bv || (ov == bv && oq < bq)) { bv = ov; bq = oq; }
    }
    __shared__ float swv[4];
    __shared__ int   swq[4];
    if (lane == 0) { swv[wave] = bv; swq[wave] = bq; }
    __syncthreads();
    if (tid == 0) {
        float v = swv[0]; int q = swq[0];
#pragma unroll
        for (int w = 1; w < 4; ++w)
            if (swv[w] > v || (swv[w] == v && swq[w] < q)) { v = swv[w]; q = swq[w]; }
        bp_pack[bg] = (v >= 0.0f)
            ? (((unsigned long long)__float_as_uint(v) << 32)
               | (unsigned long long)(~(unsigned int)q))
            : 0ull;
    }
}

// ---------------------------------------------------------------- kernel 2
// Chunked (2048 priors/block): LDS override table, exact g-rescan for
// flagged priors, CE + smooth-L1 + mine + partials + wave-aggregated
// 4096-bin LDS histogram (one atomic per distinct bin per wave).
__global__ __launch_bounds__(256) void k_loss(
    const float4* __restrict__ loc4,
    const float2* __restrict__ conf2,
    const float4* __restrict__ gt4,
    const int* __restrict__ labels,
    const float4* __restrict__ priors4,
    const unsigned char* __restrict__ match,
    const unsigned long long* __restrict__ bp_pack,
    float* __restrict__ mine,
    float* __restrict__ pl, float* __restrict__ pc, int* __restrict__ pp,
    unsigned int* __restrict__ hist1)      // [B][4096], zeroed
{
    const int b = blockIdx.y;
    const int tid = threadIdx.x;
    const int lane = tid & 63;
    const int pbase = blockIdx.x*2048;

    __shared__ float4 sgt[G_];
    __shared__ float  sarea[G_];
    __shared__ int    slab[G_];
    __shared__ signed char sovr[2048];     // override table for this p-range
    __shared__ unsigned int shist[4096];
    if (tid < G_) {
        const float4 t = gt4[b*G_ + tid];
        sgt[tid] = t;
        sarea[tid] = (t.z - t.x) * (t.w - t.y);
        slab[tid] = labels[b*G_ + tid];
    }
    for (int i = tid; i < 2048; i += 256) sovr[i] = -1;
    for (int i = tid; i < 4096; i += 256) shist[i] = 0;
    __syncthreads();
    if (tid == 0) {
        // ascending g => last-wins for duplicate best priors
        for (int g = 0; g < G_; ++g) {
            const int q = (int)(~(unsigned int)(bp_pack[b*G_ + g] & 0xFFFFFFFFull))
                        - pbase;
            if (q >= 0 && q < 2048) sovr[q] = (signed char)g;
        }
    }
    __syncthreads();

    float lL = 0.0f, pce = 0.0f; int np = 0;

#pragma unroll
    for (int c = 0; c < 8; ++c) {
        const int p = pbase + c*256 + tid;
        const bool valid = (p < P_);
        unsigned int ubin = 0;
        if (valid) {
            const int idx = b*P_ + p;
            const int og = (int)sovr[c*256 + tid];

            int cc = 0, g = 0;
            if (og >= 0) { g = og; cc = slab[g]; }
            else if (match[idx]) {
                // exact dense argmax rescan (bit-identical to k_sparse's IoU)
                const float4 pr = priors4[p];
                const float hx = pr.z * 0.5f, hy = pr.w * 0.5f;
                const float px0 = pr.x - hx, py0 = pr.y - hy;
                const float px1 = pr.x + hx, py1 = pr.y + hy;
                const float area_p = (px1 - px0) * (py1 - py0);
                float best = -1.0f;
#pragma unroll
                for (int gg = 0; gg < G_; ++gg) {
                    const float4 t = sgt[gg];
                    const float lx = fmaxf(t.x, px0), ly = fmaxf(t.y, py0);
                    const float rx = fminf(t.z, px1), ry = fminf(t.w, py1);
                    const float iw = fmaxf(rx - lx, 0.0f), ih = fmaxf(ry - ly, 0.0f);
                    const float inter = iw * ih;
                    const float iou = __fdividef(inter, (sarea[gg] + area_p) - inter);
                    if (iou > best) { best = iou; g = gg; }  // first g on tie
                }
                cc = slab[g];
            }

            const float2 x = conf2[idx];
            const float z = (cc == 0) ? (x.y - x.x) : (x.x - x.y);  // other - gold
            const float ce = __logf(1.0f + __expf(z));

            float mv = ce;
            if (cc > 0) {
                np += 1; pce += ce; mv = 0.0f;
                const float4 t  = sgt[g];
                const float4 pr = priors4[p];
                const float gcx = __fdividef((t.x + t.z)*0.5f - pr.x, 0.1f*pr.z);
                const float gcy = __fdividef((t.y + t.w)*0.5f - pr.y, 0.1f*pr.w);
                const float gw  = __logf(__fdividef(t.z - t.x, pr.z)) * 5.0f;
                const float gh  = __logf(__fdividef(t.w - t.y, pr.w)) * 5.0f;
                const float4 l = loc4[idx];
                const float d0 = fabsf(l.x - gcx);
                const float d1 = fabsf(l.y - gcy);
                const float d2 = fabsf(l.z - gw);
                const float d3 = fabsf(l.w - gh);
                lL += (d0 < 1.0f) ? 0.5f*d0*d0 : d0 - 0.5f;
                lL += (d1 < 1.0f) ? 0.5f*d1*d1 : d1 - 0.5f;
                lL += (d2 < 1.0f) ? 0.5f*d2*d2 : d2 - 0.5f;
                lL += (d3 < 1.0f) ? 0.5f*d3*d3 : d3 - 0.5f;
            }
            mine[idx] = mv;
            ubin = __float_as_uint(mv) >> 20;
        }

        // ---- wave-aggregated histogram add: one atomic per distinct bin
        unsigned long long active = __ballot(valid);
        while (active) {
            const int leader = (int)(__ffsll((long long)active) - 1);
            const unsigned int lbin = __shfl(ubin, leader, 64);
            const bool same = valid && (ubin == lbin);
            const unsigned long long samemask = __ballot(same);
            if (lane == leader)
                atomicAdd(&shist[lbin], (unsigned int)__popcll(samemask));
            active &= ~samemask;
        }
    }

    __shared__ float sL[256], sC[256];
    __shared__ int   sP[256];
    sL[tid] = lL; sC[tid] = pce; sP[tid] = np;
    __syncthreads();
    for (int off = 128; off > 0; off >>= 1) {
        if (tid < off) {
            sL[tid] += sL[tid+off];
            sC[tid] += sC[tid+off];
            sP[tid] += sP[tid+off];
        }
        __syncthreads();
    }
    if (tid == 0) {
        const int o = b*PBC_ + blockIdx.x;
        pl[o] = sL[0]; pc[o] = sC[0]; pp[o] = sP[0];
    }
    for (int i = tid; i < 4096; i += 256) {
        const unsigned int h = shist[i];
        if (h) atomicAdd(&hist1[b*4096 + i], h);
    }
}

// ---------------------------------------------------------------- kernel 3
// Per batch: np from pp partials; (t1, kk) from the 4096-bin hist1 only.
__global__ __launch_bounds__(256) void k_sel1(
    const unsigned int* __restrict__ hist1, const int* __restrict__ pp,
    int2* __restrict__ sel)
{
    const int b = blockIdx.x;
    const int tid = threadIdx.x;
    __shared__ int sred[256];
    sred[tid] = (tid < PBC_) ? pp[b*PBC_ + tid] : 0;
    __syncthreads();
    for (int off = 128; off > 0; off >>= 1) {
        if (tid < off) sred[tid] += sred[tid+off];
        __syncthreads();
    }
    const int np = sred[0];
    __syncthreads();
    int k = NEGPOS_ * np; if (k > P_-1) k = P_-1;
    if (k <= 0) { if (tid == 0) sel[b] = make_int2(0x7FFFFFFF, 0); return; }

    const unsigned int* h = hist1 + b*4096;
    const int rbase = 16*tid;                     // reversed-bin chunk
    int s = 0;
#pragma unroll
    for (int i = 0; i < 16; ++i) s += (int)h[4095 - (rbase + i)];
    __shared__ int S[256];
    S[tid] = s;
    __syncthreads();
    for (int off = 1; off < 256; off <<= 1) {
        const int t = (tid >= off) ? S[tid-off] : 0;
        __syncthreads();
        S[tid] += t;
        __syncthreads();
    }
    const int Sprev = tid ? S[tid-1] : 0;
    if (S[tid] >= k && Sprev < k) {               // exactly one thread
        int cum = Sprev;
        for (int i = 0; i < 16; ++i) {
            const int c = (int)h[4095 - (rbase + i)];
            cum += c;
            if (cum >= k) {
                sel[b] = make_int2(4095 - (rbase + i), k - (cum - c));
                break;
            }
        }
    }
}

// ---------------------------------------------------------------- kernel 4
// Chunked (2048/block): sum bins > t1; stage in-bin candidates in LDS;
// ONE global atomicAdd per block for the candidate base.
__global__ __launch_bounds__(256) void k_collect(
    const float* __restrict__ mine, const int2* __restrict__ sel,
    unsigned int* __restrict__ cand, int* __restrict__ candCount,
    float* __restrict__ pcol)
{
    const int b = blockIdx.y;
    const int tid = threadIdx.x;
    const int t1 = sel[b].x;
    const int lane = tid & 63;

    __shared__ unsigned int sbuf[2048];
    __shared__ int scnt;
    __shared__ int gbase;
    if (tid == 0) scnt = 0;
    __syncthreads();

    float sum = 0.0f;
#pragma unroll
    for (int c = 0; c < 8; ++c) {
        const int p = blockIdx.x*2048 + c*256 + tid;
        bool isCand = false;
        unsigned int u = 0;
        if (p < P_) {
            const float v = mine[(size_t)b*P_ + p];
            u = __float_as_uint(v);
            const int bin = (int)(u >> 20);
            if (bin > t1) sum += v;
            else isCand = (bin == t1);
        }
        const unsigned long long mask = __ballot(isCand);
        const int wcnt = __popcll(mask);
        int wbase = 0;
        if (lane == 0 && wcnt) wbase = atomicAdd(&scnt, wcnt);
        wbase = __shfl(wbase, 0, 64);
        if (isCand) {
            const int before = __popcll(mask & ((1ull << lane) - 1ull));
            sbuf[wbase + before] = u;
        }
    }
    __syncthreads();
    const int tot = scnt;
    if (tid == 0) gbase = tot ? atomicAdd(&candCount[b*CCSTRIDE_], tot) : 0;
    __syncthreads();
    for (int i = tid; i < tot; i += 256)
        cand[(size_t)b*P_ + gbase + i] = sbuf[i];

    __shared__ float sf[256];
    sf[tid] = sum;
    __syncthreads();
    for (int off = 128; off > 0; off >>= 1) {
        if (tid < off) sf[tid] += sf[tid+off];
        __syncthreads();
    }
    if (tid == 0) pcol[b*PBC_ + blockIdx.x] = sf[0];
}

// ---------------------------------------------------------------- kernel 5
// Per batch: refine low 20 bits over candidates (10+10), exact threshold T,
// ctop[b] = sumAbove + sum(cand > T) + (kk - cnt)*T.
__global__ __launch_bounds__(256) void k_sel2(
    const unsigned int* __restrict__ cand, const int* __restrict__ candCount,
    const int2* __restrict__ sel, const float* __restrict__ pcol,
    float* __restrict__ ctop)
{
    const int b = blockIdx.x;
    const int tid = threadIdx.x;
    __shared__ float sf[256];
    sf[tid] = (tid < PBC_) ? pcol[b*PBC_ + tid] : 0.0f;
    __syncthreads();
    for (int off = 128; off > 0; off >>= 1) {
        if (tid < off) sf[tid] += sf[tid+off];
        __syncthreads();
    }
    const float sumhi = sf[0];
    __syncthreads();

    const int2 se = sel[b];
    const int t1 = se.x, kk = se.y;
    if (kk <= 0) { if (tid == 0) ctop[b] = 0.0f; return; }
    const int nc = candCount[b*CCSTRIDE_];
    const unsigned int* row = cand + (size_t)b * P_;

    __shared__ unsigned int hist[1024];
    __shared__ int S[256];
    __shared__ int sh_b1, sh_kk2, sh_b0;

    // ---- pass 1: bits[19:10]
    for (int i = tid; i < 1024; i += 256) hist[i] = 0;
    __syncthreads();
    for (int i = tid; i < nc; i += 256)
        atomicAdd(&hist[(row[i] >> 10) & 1023u], 1u);
    __syncthreads();
    {
        const int rbase = 4*tid;
        int ls = 0;
#pragma unroll
        for (int i = 0; i < 4; ++i) ls += (int)hist[1023 - (rbase + i)];
        S[tid] = ls;
        __syncthreads();
        for (int off = 1; off < 256; off <<= 1) {
            const int t = (tid >= off) ? S[tid-off] : 0;
            __syncthreads();
            S[tid] += t;
            __syncthreads();
        }
        const int Sprev = tid ? S[tid-1] : 0;
        if (S[tid] >= kk && Sprev < kk) {
            int cum = Sprev;
            for (int i = 0; i < 4; ++i) {
                const int c = (int)hist[1023 - (rbase + i)];
                cum += c;
                if (cum >= kk) {
                    sh_b1 = 1023 - (rbase + i);
                    sh_kk2 = kk - (cum - c);
                    break;
                }
            }
        }
    }
    __syncthreads();
    const int b1 = sh_b1, kk2 = sh_kk2;

    // ---- pass 2: bits[9:0] among candidates with bits[19:10]==b1
    __syncthreads();
    for (int i = tid; i < 1024; i += 256) hist[i] = 0;
    __syncthreads();
    for (int i = tid; i < nc; i += 256) {
        const unsigned int u = row[i];
        if (((u >> 10) & 1023u) == (unsigned int)b1)
            atomicAdd(&hist[u & 1023u], 1u);
    }
    __syncthreads();
    {
        const int rbase = 4*tid;
        int ls = 0;
#pragma unroll
        for (int i = 0; i < 4; ++i) ls += (int)hist[1023 - (rbase + i)];
        S[tid] = ls;
        __syncthreads();
        for (int off = 1; off < 256; off <<= 1) {
            const int t = (tid >= off) ? S[tid-off] : 0;
            __syncthreads();
            S[tid] += t;
            __syncthreads();
        }
        const int Sprev = tid ? S[tid-1] : 0;
        if (S[tid] >= kk2 && Sprev < kk2) {
            int cum = Sprev;
            for (int i = 0; i < 4; ++i) {
                const int c = (int)hist[1023 - (rbase + i)];
                cum += c;
                if (cum >= kk2) { sh_b0 = 1023 - (rbase + i); break; }
            }
        }
    }
    __syncthreads();
    const unsigned int Tbits =
        ((unsigned int)t1 << 20) | ((unsigned int)b1 << 10) | (unsigned int)sh_b0;
    const float T = __uint_as_float(Tbits);

    float sumc = 0.0f; int cnt = 0;
    for (int i = tid; i < nc; i += 256) {
        const unsigned int u = row[i];
        if (u > Tbits) { sumc += __uint_as_float(u); ++cnt; }
    }
    __shared__ int sci[256];
    sf[tid] = sumc; sci[tid] = cnt;
    __syncthreads();
    for (int off = 128; off > 0; off >>= 1) {
        if (tid < off) { sf[tid] += sf[tid+off]; sci[tid] += sci[tid+off]; }
        __syncthreads();
    }
    if (tid == 0)
        ctop[b] = sumhi + sf[0] + (float)(kk - sci[0]) * T;
}

// ---------------------------------------------------------------- kernel 6
__global__ __launch_bounds__(256) void k_final(
    const float* __restrict__ pl, const float* __restrict__ pc,
    const int* __restrict__ pp, const float* __restrict__ ctop,
    float* __restrict__ out)
{
    const int tid = threadIdx.x;
    float sL = 0.0f, sC = 0.0f; int tp = 0;
    for (int i = tid; i < NBLK_; i += 256) {
        sL += pl[i]; sC += pc[i]; tp += pp[i];
    }
    float sT = (tid < B_) ? ctop[tid] : 0.0f;
    __shared__ float aL[256], aC[256], aT[256];
    __shared__ int   aP[256];
    aL[tid] = sL; aC[tid] = sC; aT[tid] = sT; aP[tid] = tp;
    __syncthreads();
    for (int off = 128; off > 0; off >>= 1) {
        if (tid < off) {
            aL[tid] += aL[tid+off];
            aC[tid] += aC[tid+off];
            aT[tid] += aT[tid+off];
            aP[tid] += aP[tid+off];
        }
        __syncthreads();
    }
    if (tid == 0) {
        const float N = fmaxf((float)aP[0], 1.0f);
        out[0] = (2.0f*aL[0] + aC[0] + aT[0]) / N;
    }
}

// ----------------------------------------------------------------
extern "C" void kernel_launch(void* const* d_in, const int* in_sizes, int n_in,
                              void* d_out, int out_size, void* d_ws, size_t ws_size,
                              hipStream_t stream)
{
    const float* loc    = (const float*)d_in[0];   // [B,P,4]
    const float* conf   = (const float*)d_in[1];   // [B,P,2]
    const float* gt     = (const float*)d_in[2];   // [B,G,4]
    const int*   labels = (const int*)d_in[3];     // [B,G]
    const float* priors = (const float*)d_in[4];   // [P,4]
    float* out = (float*)d_out;

    char* ws = (char*)d_ws;
    size_t off = 0;
    // --- zeroed region (filled by k_zero) ---
    unsigned char* match = (unsigned char*)(ws + off); off += (size_t)B_*P_;     // 1.86 MB
    unsigned int* hist1 = (unsigned int*)(ws + off);   off += (size_t)B_*4096*4; // 1 MB
    int* candCount = (int*)(ws + off);                 off += (size_t)B_*CCSTRIDE_*4;
    // --- rest ---
    off = (off + 255) & ~255ull;
    unsigned long long* bp_pack =
        (unsigned long long*)(ws + off);             off += (size_t)B_*G_*8;
    float* mine = (float*)(ws + off);                off += (size_t)B_*P_*4;
    float* pl   = (float*)(ws + off);                off += (size_t)NBLK_*4;
    float* pc   = (float*)(ws + off);                off += (size_t)NBLK_*4;
    int*   pp   = (int*)(ws + off);                  off += (size_t)NBLK_*4;
    float* pcol = (float*)(ws + off);                off += (size_t)NBLK_*4;
    unsigned int* cand = (unsigned int*)(ws + off);  off += (size_t)B_*P_*4;
    int2*  sel  = (int2*)(ws + off);                 off += (size_t)B_*8;
    float* ctop = (float*)(ws + off);                off += (size_t)B_*4;

    k_zero<<<dim3((ZVEC_ + 255)/256), dim3(256), 0, stream>>>((ulonglong2*)ws);
    k_sparse<<<dim3(G_, B_), dim3(256), 0, stream>>>(
        (const float4*)gt, (const float4*)priors, match, bp_pack);
    k_loss<<<dim3(PBC_, B_), dim3(256), 0, stream>>>(
        (const float4*)loc, (const float2*)conf, (const float4*)gt, labels,
        (const float4*)priors, match, bp_pack, mine, pl, pc, pp, hist1);
    k_sel1<<<dim3(B_), dim3(256), 0, stream>>>(hist1, pp, sel);
    k_collect<<<dim3(PBC_, B_), dim3(256), 0, stream>>>(mine, sel, cand, candCount, pcol);
    k_sel2<<<dim3(B_), dim3(256), 0, stream>>>(cand, candCount, sel, pcol, ctop);
    k_final<<<dim3(1), dim3(256), 0, stream>>>(pl, pc, pp, ctop, out);
}

// Round 14
// 75.687 us; speedup vs baseline: 1.3076x; 1.3076x over previous
//
#include <hip/hip_runtime.h>

// SSD MultiBoxLoss: B=64, P=29126, G=24, 2 classes, scalar fp32 output.
// Sparse matching -> byte flags. NO histogram: k_loss counts a fixed
// 16-threshold ladder (register-packed, no atomics); k_sel1 picks the
// bracket containing the k-th value; k_collect compacts in-bracket
// candidates; k_sel2 radix-selects exactly among them.
static constexpr int B_ = 64;
static constexpr int P_ = 29126;
static constexpr int G_ = 24;
static constexpr float THRESH_ = 0.35f;
static constexpr int NEGPOS_ = 7;
static constexpr int PBL_ = (P_ + 1023) / 1024;   // 29 p-blocks (1024 each)
static constexpr int NBL_ = PBL_ * B_;            // 1856 partial slots
static constexpr int CCSTRIDE_ = 32;              // candCount stride = 128 B

// ladder (must match the literals in k_loss exactly)
__device__ const float LAD_[16] = {
    0.5f,    0.5901f, 0.6964f, 0.8220f, 0.9701f, 1.1450f, 1.3514f, 1.5950f,
    1.8825f, 2.2218f, 2.6223f, 3.0950f, 3.6529f, 4.3113f, 5.0885f, 6.0057f };

// zeroed region: match (B*P bytes) + candCount
static constexpr size_t ZBYTES_ = (size_t)B_*P_ + (size_t)B_*CCSTRIDE_*4;
static constexpr int ZVEC_ = (int)((ZBYTES_ + 15) / 16);

// ---------------------------------------------------------------- kernel 0
__global__ __launch_bounds__(256) void k_zero(ulonglong2* __restrict__ dst)
{
    const int i = blockIdx.x*256 + threadIdx.x;
    if (i < ZVEC_) dst[i] = make_ulonglong2(0ull, 0ull);
}

// ---------------------------------------------------------------- kernel 1
// One block per (b,g). Enumerate intersecting priors.
//   match[b,p] = 1 (plain byte store) when iou >= THRESH  -- no atomics.
//   bp_pack[b,g] = (iou_bits<<32)|~p  (tie => min p), plain store.
__global__ __launch_bounds__(256) void k_sparse(
    const float4* __restrict__ gt4,      // [B*G] point-form
    const float4* __restrict__ priors4,  // [P]  (cx,cy,w,h)
    unsigned char* __restrict__ match,   // [B*P], zeroed
    unsigned long long* __restrict__ bp_pack)   // [B*G]
{
    const int g = blockIdx.x;            // G_
    const int b = blockIdx.y;            // B_
    const int bg = b*G_ + g;
    const int tid = threadIdx.x;

    const float4 t = gt4[bg];
    const float area_t = (t.z - t.x) * (t.w - t.y);

    float bv = -1.0f; int bq = 0;

#pragma unroll
    for (int r = 0; r < 6; ++r) {
        const int   f    = (r < 2) ? 105 : (r < 4) ? 53 : 27;
        const float sc   = (r < 2) ? 105.0f : (r < 4) ? 52.5f : 26.25f; // 840/step
        const int   base = (r == 0) ? 0 : (r == 1) ? 11025 : (r == 2) ? 22050
                         : (r == 3) ? 24859 : (r == 4) ? 27668 : 28397;
        const float hw   = ((r == 0) ? 16.0f : (r == 1) ? 32.0f : (r == 2) ? 64.0f
                         : (r == 3) ? 128.0f : (r == 4) ? 256.0f : 512.0f)
                           * (0.5f / 840.0f);

        const int j0 = max(0,     (int)floorf((t.x - hw)*sc - 0.5f) - 1);
        const int j1 = min(f - 1, (int)ceilf ((t.z + hw)*sc - 0.5f) + 1);
        const int i0 = max(0,     (int)floorf((t.y - hw)*sc - 0.5f) - 1);
        const int i1 = min(f - 1, (int)ceilf ((t.w + hw)*sc - 0.5f) + 1);
        const int W = j1 - j0 + 1;
        const int n = W * (i1 - i0 + 1);

        for (int c = tid; c < n; c += 256) {
            const int ii = c / W;
            const int jj = c - ii*W;
            const int p = base + (i0 + ii)*f + (j0 + jj);
            const float4 pr = priors4[p];
            const float hx = pr.z * 0.5f, hy = pr.w * 0.5f;
            const float px0 = pr.x - hx, py0 = pr.y - hy;
            const float px1 = pr.x + hx, py1 = pr.y + hy;
            const float area_p = (px1 - px0) * (py1 - py0);
            const float lx = fmaxf(t.x, px0), ly = fmaxf(t.y, py0);
            const float rx = fminf(t.z, px1), ry = fminf(t.w, py1);
            const float iw = fmaxf(rx - lx, 0.0f), ih = fmaxf(ry - ly, 0.0f);
            const float inter = iw * ih;
            const float iou = __fdividef(inter, (area_t + area_p) - inter);

            if (iou >= THRESH_) match[(size_t)b*P_ + p] = 1;
            if (iou > bv) { bv = iou; bq = p; }   // increasing p => min-p tie
        }
    }

    // block argmax (max iou, tie => min p)
    const int lane = tid & 63, wave = tid >> 6;
    for (int m = 32; m; m >>= 1) {
        const float ov = __shfl_xor(bv, m, 64);
        const int   oq = __shfl_xor(bq, m, 64);
        if (ov > bv || (ov == bv && oq < bq)) { bv = ov; bq = oq; }
    }
    __shared__ float swv[4];
    __shared__ int   swq[4];
    if (lane == 0) { swv[wave] = bv; swq[wave] = bq; }
    __syncthreads();
    if (tid == 0) {
        float v = swv[0]; int q = swq[0];
#pragma unroll
        for (int w = 1; w < 4; ++w)
            if (swv[w] > v || (swv[w] == v && swq[w] < q)) { v = swv[w]; q = swq[w]; }
        bp_pack[bg] = (v >= 0.0f)
            ? (((unsigned long long)__float_as_uint(v) << 32)
               | (unsigned long long)(~(unsigned int)q))
            : 0ull;
    }
}

// ---------------------------------------------------------------- kernel 2
// Chunked (1024 priors/block): LDS override table, exact g-rescan for
// flagged priors, CE + smooth-L1 + mine + partials + 16-threshold ladder
// counts packed in registers (no histogram, no atomics).
__global__ __launch_bounds__(256) void k_loss(
    const float4* __restrict__ loc4,
    const float2* __restrict__ conf2,
    const float4* __restrict__ gt4,
    const int* __restrict__ labels,
    const float4* __restrict__ priors4,
    const unsigned char* __restrict__ match,
    const unsigned long long* __restrict__ bp_pack,
    float* __restrict__ mine,
    float* __restrict__ pl, float* __restrict__ pc, int* __restrict__ pp,
    unsigned int* __restrict__ pcnt)       // [NBL_][8] packed u16 pairs
{
    const int b = blockIdx.y;
    const int tid = threadIdx.x;
    const int pbase = blockIdx.x*1024;

    __shared__ float4 sgt[G_];
    __shared__ float  sarea[G_];
    __shared__ int    slab[G_];
    __shared__ signed char sovr[1024];
    if (tid < G_) {
        const float4 t = gt4[b*G_ + tid];
        sgt[tid] = t;
        sarea[tid] = (t.z - t.x) * (t.w - t.y);
        slab[tid] = labels[b*G_ + tid];
    }
    for (int i = tid; i < 1024; i += 256) sovr[i] = -1;
    __syncthreads();
    if (tid == 0) {
        // ascending g => last-wins for duplicate best priors
        for (int g = 0; g < G_; ++g) {
            const int q = (int)(~(unsigned int)(bp_pack[b*G_ + g] & 0xFFFFFFFFull))
                        - pbase;
            if (q >= 0 && q < 1024) sovr[q] = (signed char)g;
        }
    }
    __syncthreads();

    float lL = 0.0f, pce = 0.0f; int np = 0;
    unsigned q0 = 0, q1 = 0, q2 = 0, q3 = 0, q4 = 0, q5 = 0, q6 = 0, q7 = 0;

#pragma unroll
    for (int c = 0; c < 4; ++c) {
        const int p = pbase + c*256 + tid;
        if (p < P_) {
            const int idx = b*P_ + p;
            const int og = (int)sovr[c*256 + tid];

            int cc = 0, g = 0;
            if (og >= 0) { g = og; cc = slab[g]; }
            else if (match[idx]) {
                // exact dense argmax rescan (bit-identical to k_sparse's IoU)
                const float4 pr = priors4[p];
                const float hx = pr.z * 0.5f, hy = pr.w * 0.5f;
                const float px0 = pr.x - hx, py0 = pr.y - hy;
                const float px1 = pr.x + hx, py1 = pr.y + hy;
                const float area_p = (px1 - px0) * (py1 - py0);
                float best = -1.0f;
#pragma unroll
                for (int gg = 0; gg < G_; ++gg) {
                    const float4 t = sgt[gg];
                    const float lx = fmaxf(t.x, px0), ly = fmaxf(t.y, py0);
                    const float rx = fminf(t.z, px1), ry = fminf(t.w, py1);
                    const float iw = fmaxf(rx - lx, 0.0f), ih = fmaxf(ry - ly, 0.0f);
                    const float inter = iw * ih;
                    const float iou = __fdividef(inter, (sarea[gg] + area_p) - inter);
                    if (iou > best) { best = iou; g = gg; }  // first g on tie
                }
                cc = slab[g];
            }

            const float2 x = conf2[idx];
            const float z = (cc == 0) ? (x.y - x.x) : (x.x - x.y);  // other - gold
            const float ce = __logf(1.0f + __expf(z));

            float mv = ce;
            if (cc > 0) {
                np += 1; pce += ce; mv = 0.0f;
                const float4 t  = sgt[g];
                const float4 pr = priors4[p];
                const float gcx = __fdividef((t.x + t.z)*0.5f - pr.x, 0.1f*pr.z);
                const float gcy = __fdividef((t.y + t.w)*0.5f - pr.y, 0.1f*pr.w);
                const float gw  = __logf(__fdividef(t.z - t.x, pr.z)) * 5.0f;
                const float gh  = __logf(__fdividef(t.w - t.y, pr.w)) * 5.0f;
                const float4 l = loc4[idx];
                const float d0 = fabsf(l.x - gcx);
                const float d1 = fabsf(l.y - gcy);
                const float d2 = fabsf(l.z - gw);
                const float d3 = fabsf(l.w - gh);
                lL += (d0 < 1.0f) ? 0.5f*d0*d0 : d0 - 0.5f;
                lL += (d1 < 1.0f) ? 0.5f*d1*d1 : d1 - 0.5f;
                lL += (d2 < 1.0f) ? 0.5f*d2*d2 : d2 - 0.5f;
                lL += (d3 < 1.0f) ? 0.5f*d3*d3 : d3 - 0.5f;
            }
            mine[idx] = mv;

            // ladder counts (literals must match LAD_ exactly)
            q0 += (unsigned)(mv > 0.5f)    + ((unsigned)(mv > 0.5901f) << 16);
            q1 += (unsigned)(mv > 0.6964f) + ((unsigned)(mv > 0.8220f) << 16);
            q2 += (unsigned)(mv > 0.9701f) + ((unsigned)(mv > 1.1450f) << 16);
            q3 += (unsigned)(mv > 1.3514f) + ((unsigned)(mv > 1.5950f) << 16);
            q4 += (unsigned)(mv > 1.8825f) + ((unsigned)(mv > 2.2218f) << 16);
            q5 += (unsigned)(mv > 2.6223f) + ((unsigned)(mv > 3.0950f) << 16);
            q6 += (unsigned)(mv > 3.6529f) + ((unsigned)(mv > 4.3113f) << 16);
            q7 += (unsigned)(mv > 5.0885f) + ((unsigned)(mv > 6.0057f) << 16);
        }
    }

    __shared__ float sL[256], sC[256];
    __shared__ int   sP[256];
    __shared__ unsigned su[8][256];
    sL[tid] = lL; sC[tid] = pce; sP[tid] = np;
    su[0][tid] = q0; su[1][tid] = q1; su[2][tid] = q2; su[3][tid] = q3;
    su[4][tid] = q4; su[5][tid] = q5; su[6][tid] = q6; su[7][tid] = q7;
    __syncthreads();
    for (int off = 128; off > 0; off >>= 1) {
        if (tid < off) {
            sL[tid] += sL[tid+off];
            sC[tid] += sC[tid+off];
            sP[tid] += sP[tid+off];
#pragma unroll
            for (int j = 0; j < 8; ++j) su[j][tid] += su[j][tid+off];
        }
        __syncthreads();
    }
    const int o = b*PBL_ + blockIdx.x;
    if (tid == 0) { pl[o] = sL[0]; pc[o] = sC[0]; pp[o] = sP[0]; }
    if (tid < 8) pcnt[o*8 + tid] = su[tid][0];
}

// ---------------------------------------------------------------- kernel 3
// Per batch: np from pp; ladder counts C[16]; bracket (lo, hi] containing
// the k-th value; sel = {hi_bits, lo_bits, kk}.
__global__ __launch_bounds__(256) void k_sel1(
    const unsigned int* __restrict__ pcnt, const int* __restrict__ pp,
    int4* __restrict__ sel)
{
    const int b = blockIdx.x;
    const int tid = threadIdx.x;
    __shared__ int sred[256];
    sred[tid] = (tid < PBL_) ? pp[b*PBL_ + tid] : 0;
    __syncthreads();
    for (int off = 128; off > 0; off >>= 1) {
        if (tid < off) sred[tid] += sred[tid+off];
        __syncthreads();
    }
    const int np = sred[0];
    int k = NEGPOS_ * np; if (k > P_-1) k = P_-1;

    __shared__ unsigned red[32][8];
    {
        const int i = tid >> 3, j = tid & 7;
        red[i][j] = (i < PBL_) ? pcnt[(b*PBL_ + i)*8 + j] : 0u;
    }
    __syncthreads();
    for (int off = 16; off > 0; off >>= 1) {
        const int i = tid >> 3, j = tid & 7;
        if (i < off) red[i][j] += red[i+off][j];
        __syncthreads();
    }
    __shared__ int C[16];
    if (tid < 8) {
        C[2*tid]   = (int)(red[0][tid] & 0xFFFFu);
        C[2*tid+1] = (int)(red[0][tid] >> 16);
    }
    __syncthreads();
    if (tid == 0) {
        int4 s; s.w = 0;
        if (k <= 0) {
            s.x = 0x7F800000; s.y = 0x7F800000; s.z = 0;   // no negs selected
        } else {
            int js = -1;
            for (int j = 0; j < 16; ++j) if (C[j] >= k) js = j;
            if (js < 0) {                 // k-th value <= T0: cand = v <= T0
                s.x = __float_as_int(LAD_[0]);
                s.y = __float_as_int(-1.0f);               // v > -1 always
                s.z = k - C[0];
            } else if (js == 15) {        // k-th value > T15: cand = v > T15
                s.x = 0x7F800000;
                s.y = __float_as_int(LAD_[15]);
                s.z = k;
            } else {                      // in (T_js, T_{js+1}]
                s.x = __float_as_int(LAD_[js+1]);
                s.y = __float_as_int(LAD_[js]);
                s.z = k - C[js+1];
            }
        }
        sel[b] = s;
    }
}

// ---------------------------------------------------------------- kernel 4
// Chunked (1024/block): sum v > hi; compact candidates (lo < v <= hi) via
// ballot -> LDS staging -> ONE global atomicAdd per block.
__global__ __launch_bounds__(256) void k_collect(
    const float* __restrict__ mine, const int4* __restrict__ sel,
    unsigned int* __restrict__ cand, int* __restrict__ candCount,
    float* __restrict__ pcol)
{
    const int b = blockIdx.y;
    const int tid = threadIdx.x;
    const int lane = tid & 63;
    const int4 se = sel[b];
    const float hi = __int_as_float(se.x);
    const float lo = __int_as_float(se.y);

    __shared__ unsigned int sbuf[1024];
    __shared__ int scnt;
    __shared__ int gbase;
    if (tid == 0) scnt = 0;
    __syncthreads();

    float sum = 0.0f;
#pragma unroll
    for (int c = 0; c < 4; ++c) {
        const int p = blockIdx.x*1024 + c*256 + tid;
        bool isCand = false;
        unsigned int u = 0;
        if (p < P_) {
            const float v = mine[(size_t)b*P_ + p];
            u = __float_as_uint(v);
            if (v > hi) sum += v;
            else isCand = (v > lo);
        }
        const unsigned long long mask = __ballot(isCand);
        const int wcnt = __popcll(mask);
        int wbase = 0;
        if (lane == 0 && wcnt) wbase = atomicAdd(&scnt, wcnt);
        wbase = __shfl(wbase, 0, 64);
        if (isCand) {
            const int before = __popcll(mask & ((1ull << lane) - 1ull));
            sbuf[wbase + before] = u;
        }
    }
    __syncthreads();
    const int tot = scnt;
    if (tid == 0) gbase = tot ? atomicAdd(&candCount[b*CCSTRIDE_], tot) : 0;
    __syncthreads();
    for (int i = tid; i < tot; i += 256)
        cand[(size_t)b*P_ + gbase + i] = sbuf[i];

    __shared__ float sf[256];
    sf[tid] = sum;
    __syncthreads();
    for (int off = 128; off > 0; off >>= 1) {
        if (tid < off) sf[tid] += sf[tid+off];
        __syncthreads();
    }
    if (tid == 0) pcol[b*PBL_ + blockIdx.x] = sf[0];
}

// ---------------------------------------------------------------- kernel 5
// Per batch: exact kk-th threshold among candidates via 4x8-bit radix;
// ctop[b] = sumAbove + sum(cand > T) + (kk - cnt)*T.
__global__ __launch_bounds__(256) void k_sel2(
    const unsigned int* __restrict__ cand, const int* __restrict__ candCount,
    const int4* __restrict__ sel, const float* __restrict__ pcol,
    float* __restrict__ ctop)
{
    const int b = blockIdx.x;
    const int tid = threadIdx.x;
    __shared__ float sf[256];
    sf[tid] = (tid < PBL_) ? pcol[b*PBL_ + tid] : 0.0f;
    __syncthreads();
    for (int off = 128; off > 0; off >>= 1) {
        if (tid < off) sf[tid] += sf[tid+off];
        __syncthreads();
    }
    const float sumhi = sf[0];
    __syncthreads();

    const int kk = sel[b].z;
    const int nc = candCount[b*CCSTRIDE_];
    if (kk <= 0 || nc <= 0) { if (tid == 0) ctop[b] = sumhi; return; }
    const unsigned int* row = cand + (size_t)b * P_;

    __shared__ unsigned int hist[256];
    __shared__ unsigned int sc0[256], sc1[256];
    __shared__ unsigned int sh_prefix;
    __shared__ int sh_kk;

    unsigned int prefix = 0; int kk2 = kk;
    for (int pass = 3; pass >= 0; --pass) {
        hist[tid] = 0;
        __syncthreads();
        const unsigned int highmask =
            (pass == 3) ? 0u : (0xFFFFFFFFu << ((pass+1)*8));
        for (int i = tid; i < nc; i += 256) {
            const unsigned int u = row[i];
            if ((u & highmask) == (prefix & highmask))
                atomicAdd(&hist[(u >> (pass*8)) & 255u], 1u);
        }
        __syncthreads();
        sc0[tid] = hist[255 - tid];              // reversed bins
        __syncthreads();
        unsigned int* src = sc0; unsigned int* dst = sc1;
        for (int off = 1; off < 256; off <<= 1) {
            unsigned int v = src[tid];
            if (tid >= off) v += src[tid - off];
            dst[tid] = v;
            __syncthreads();
            unsigned int* t = src; src = dst; dst = t;
        }
        {
            const int bin = 255 - tid;
            const int cum = (int)src[tid];
            const int cumPrev = (tid == 0) ? 0 : (int)src[tid-1];
            if (cum >= kk2 && cumPrev < kk2) {   // exactly one thread
                sh_prefix = prefix | ((unsigned int)bin << (pass*8));
                sh_kk = kk2 - cumPrev;
            }
        }
        __syncthreads();
        prefix = sh_prefix; kk2 = sh_kk;
        __syncthreads();
    }

    const float T = __uint_as_float(prefix);
    float sum = 0.0f; int cnt = 0;
    for (int i = tid; i < nc; i += 256) {
        const unsigned int u = row[i];
        if (u > prefix) { sum += __uint_as_float(u); ++cnt; }
    }
    __shared__ int sci[256];
    sf[tid] = sum; sci[tid] = cnt;
    __syncthreads();
    for (int off = 128; off > 0; off >>= 1) {
        if (tid < off) { sf[tid] += sf[tid+off]; sci[tid] += sci[tid+off]; }
        __syncthreads();
    }
    if (tid == 0)
        ctop[b] = sumhi + sf[0] + (float)(kk - sci[0]) * T;
}

// ---------------------------------------------------------------- kernel 6
__global__ __launch_bounds__(256) void k_final(
    const float* __restrict__ pl, const float* __restrict__ pc,
    const int* __restrict__ pp, const float* __restrict__ ctop,
    float* __restrict__ out)
{
    const int tid = threadIdx.x;
    float sL = 0.0f, sC = 0.0f; int tp = 0;
    for (int i = tid; i < NBL_; i += 256) {
        sL += pl[i]; sC += pc[i]; tp += pp[i];
    }
    float sT = (tid < B_) ? ctop[tid] : 0.0f;
    __shared__ float aL[256], aC[256], aT[256];
    __shared__ int   aP[256];
    aL[tid] = sL; aC[tid] = sC; aT[tid] = sT; aP[tid] = tp;
    __syncthreads();
    for (int off = 128; off > 0; off >>= 1) {
        if (tid < off) {
            aL[tid] += aL[tid+off];
            aC[tid] += aC[tid+off];
            aT[tid] += aT[tid+off];
            aP[tid] += aP[tid+off];
        }
        __syncthreads();
    }
    if (tid == 0) {
        const float N = fmaxf((float)aP[0], 1.0f);
        out[0] = (2.0f*aL[0] + aC[0] + aT[0]) / N;
    }
}

// ----------------------------------------------------------------
extern "C" void kernel_launch(void* const* d_in, const int* in_sizes, int n_in,
                              void* d_out, int out_size, void* d_ws, size_t ws_size,
                              hipStream_t stream)
{
    const float* loc    = (const float*)d_in[0];   // [B,P,4]
    const float* conf   = (const float*)d_in[1];   // [B,P,2]
    const float* gt     = (const float*)d_in[2];   // [B,G,4]
    const int*   labels = (const int*)d_in[3];     // [B,G]
    const float* priors = (const float*)d_in[4];   // [P,4]
    float* out = (float*)d_out;

    char* ws = (char*)d_ws;
    size_t off = 0;
    // --- zeroed region (filled by k_zero) ---
    unsigned char* match = (unsigned char*)(ws + off); off += (size_t)B_*P_;  // 1.86 MB
    int* candCount = (int*)(ws + off);                 off += (size_t)B_*CCSTRIDE_*4;
    // --- rest ---
    off = (off + 255) & ~255ull;
    unsigned long long* bp_pack =
        (unsigned long long*)(ws + off);             off += (size_t)B_*G_*8;
    float* mine = (float*)(ws + off);                off += (size_t)B_*P_*4;
    float* pl   = (float*)(ws + off);                off += (size_t)NBL_*4;
    float* pc   = (float*)(ws + off);                off += (size_t)NBL_*4;
    int*   pp   = (int*)(ws + off);                  off += (size_t)NBL_*4;
    float* pcol = (float*)(ws + off);                off += (size_t)NBL_*4;
    unsigned int* pcnt = (unsigned int*)(ws + off);  off += (size_t)NBL_*8*4;
    unsigned int* cand = (unsigned int*)(ws + off);  off += (size_t)B_*P_*4;
    int4*  sel  = (int4*)(ws + off);                 off += (size_t)B_*16;
    float* ctop = (float*)(ws + off);                off += (size_t)B_*4;

    k_zero<<<dim3((ZVEC_ + 255)/256), dim3(256), 0, stream>>>((ulonglong2*)ws);
    k_sparse<<<dim3(G_, B_), dim3(256), 0, stream>>>(
        (const float4*)gt, (const float4*)priors, match, bp_pack);
    k_loss<<<dim3(PBL_, B_), dim3(256), 0, stream>>>(
        (const float4*)loc, (const float2*)conf, (const float4*)gt, labels,
        (const float4*)priors, match, bp_pack, mine, pl, pc, pp, pcnt);
    k_sel1<<<dim3(B_), dim3(256), 0, stream>>>(pcnt, pp, sel);
    k_collect<<<dim3(PBL_, B_), dim3(256), 0, stream>>>(mine, sel, cand, candCount, pcol);
    k_sel2<<<dim3(B_), dim3(256), 0, stream>>>(cand, candCount, sel, pcol, ctop);
    k_final<<<dim3(1), dim3(256), 0, stream>>>(pl, pc, pp, ctop, out);
}